// Round 5
// baseline (661.040 us; speedup 1.0000x reference)
//
#include <hip/hip_runtime.h>
#include <math.h>

constexpr int BB = 64, NN = 512, DD = 128, UU = 64;
constexpr float KCOUL = 14.399645351950548f;
constexpr float NOISEF = 1e-8f;
#define M_PIF 3.14159265358979323846f

typedef __attribute__((ext_vector_type(8))) short bfrag;   // 8 bf16 (4 VGPRs)
typedef __attribute__((ext_vector_type(4))) float ffrag;   // 4 fp32 acc

__device__ __forceinline__ unsigned short f2bf(float f) {   // RNE float->bf16
  unsigned int u = __float_as_uint(f);
  u += 0x7fffu + ((u >> 16) & 1u);
  return (unsigned short)(u >> 16);
}

// ---------------- chi MLP: one wave (64 lanes) per row, 4 rows/block ----------
__global__ __launch_bounds__(256) void chi_kernel(
    const float* __restrict__ feats, const float* __restrict__ W1,
    const float* __restrict__ b1, const float* __restrict__ W2,
    const float* __restrict__ b2, const float* __restrict__ W3,
    const float* __restrict__ b3, float* __restrict__ chi)
{
  int wave = threadIdx.x >> 6, lane = threadIdx.x & 63;
  int row = (blockIdx.x << 2) + wave;
  __shared__ float sf[4][DD];
  __shared__ float sh[4][UU];
  const float* f = feats + (size_t)row * DD;
  sf[wave][lane] = f[lane];
  sf[wave][lane + 64] = f[lane + 64];
  __syncthreads();
  float a = b1[lane];
  #pragma unroll 8
  for (int d = 0; d < DD; ++d) a = fmaf(sf[wave][d], W1[d * UU + lane], a);
  float h1 = a - tanhf(a);            // tanhshrink
  sh[wave][lane] = h1;
  __syncthreads();
  float a2 = b2[lane];
  #pragma unroll 8
  for (int i = 0; i < UU; ++i) a2 = fmaf(sh[wave][i], W2[i * UU + lane], a2);
  float h2 = a2 - tanhf(a2);
  float prod = h2 * W3[lane];
  #pragma unroll
  for (int off = 32; off; off >>= 1) prod += __shfl_down(prod, off, 64);
  if (lane == 0) {
    float z = prod + b3[0];
    chi[row] = z - tanhf(z);
  }
}

// ------------- build A (fp32 to d_out) + optional bf16 copy (to ws) ----------
__global__ __launch_bounds__(256) void build_A_kernel(
    const float* __restrict__ pos, const int* __restrict__ ntype,
    const float* __restrict__ hardness, const float* __restrict__ sigma,
    float* __restrict__ Aout, unsigned short* __restrict__ Abf)
{
  int b = blockIdx.y;
  int r0 = blockIdx.x * 16;
  __shared__ float px[NN], py[NN], pz[NN], s2[NN], hd[NN];
  for (int n = threadIdx.x; n < NN; n += 256) {
    const float* p = pos + ((size_t)b * NN + n) * 3;
    px[n] = p[0]; py[n] = p[1]; pz[n] = p[2];
    int ty = ntype[b * NN + n];
    float s = sigma[ty];
    s2[n] = s * s;
    hd[n] = hardness[ty];
  }
  __syncthreads();
  int c0 = (threadIdx.x & 127) << 2;
  int rsub = threadIdx.x >> 7;
  float* outB = Aout + (size_t)b * NN * NN;
  unsigned short* bfB = Abf ? Abf + (size_t)b * NN * NN : nullptr;
  for (int k = 0; k < 8; ++k) {
    int i = r0 + (k << 1) + rsub;
    float pxi = px[i], pyi = py[i], pzi = pz[i], s2i = s2[i];
    float4 v;
    float* vp = &v.x;
    #pragma unroll
    for (int c = 0; c < 4; ++c) {
      int j = c0 + c;
      float dx = pxi - px[j], dy = pyi - py[j], dz = pzi - pz[j];
      float d = sqrtf(fmaf(dx, dx, fmaf(dy, dy, dz * dz))) + NOISEF;
      float arg = d * rsqrtf(2.0f * (s2i + s2[j]));
      float val = KCOUL * erff(arg) / d;
      if (j == i) val += hd[i] + KCOUL * rsqrtf(2.0f * M_PIF * s2i);
      vp[c] = val;
    }
    *reinterpret_cast<float4*>(outB + (size_t)i * NN + c0) = v;
    if (bfB) {
      ushort4 w;
      w.x = f2bf(v.x); w.y = f2bf(v.y); w.z = f2bf(v.z); w.w = f2bf(v.w);
      *reinterpret_cast<ushort4*>(bfB + (size_t)i * NN + c0) = w;
    }
  }
}

// ---------------- shared reduction helper ------------------------------------
__device__ __forceinline__ float2 blockReduce2(float2 v, float2* wred, int t) {
  #pragma unroll
  for (int off = 32; off; off >>= 1) {
    v.x += __shfl_down(v.x, off, 64);
    v.y += __shfl_down(v.y, off, 64);
  }
  __syncthreads();
  if ((t & 63) == 0) wred[t >> 6] = v;
  __syncthreads();
  float2 r = wred[0];
  #pragma unroll
  for (int k = 1; k < 16; ++k) { r.x += wred[k].x; r.y += wred[k].y; }
  return r;
}

// ------------- MFMA-matvec 2-RHS CG, one 1024-thread block per batch ---------
// matvec q = A p as bf16 MFMA 16x16x32: wave w owns rows [32w, 32w+32)
// (two 16-row tiles), accumulating full q-rows in D regs -> no fold phase.
__global__ __launch_bounds__(1024) void cg_kernel_bf(
    const unsigned short* __restrict__ Abf, const float* __restrict__ tq,
    float* __restrict__ qout /* in: chi, out: charges */)
{
  int b = blockIdx.x;
  const unsigned short* A = Abf + (size_t)b * NN * NN;
  int t = threadIdx.x;
  int lane = t & 63, w = t >> 6;          // 16 waves
  __shared__ float2 p01[NN], q01[NN], r01[NN], x01[NN];
  __shared__ unsigned short pbf[16][4][16][8];  // [chunk][quad][n][e]  16 KB
  __shared__ float2 wred[16];

  // zero pbf once (cols n>=2 stay 0 forever -> D cols 2..15 are exactly 0)
  reinterpret_cast<uint4*>(pbf)[t] = make_uint4(0u, 0u, 0u, 0u);

  float2 z2 = make_float2(0.f, 0.f);
  float2 rsq = z2;
  if (t < NN) {
    float b0 = -qout[b * NN + t];          // rhs0 = -chi ; rhs1 = ones
    x01[t] = z2;
    r01[t] = make_float2(b0, 1.0f);
    p01[t] = make_float2(b0, 1.0f);
    rsq = make_float2(b0 * b0, 1.0f);
  }
  float2 rr = blockReduce2(rsq, wred, t);  // also publishes p01 / zeros of pbf
  float tol0 = fmaxf(1e-6f * rr.x, 1e-12f);   // rel residual 1e-3
  float tol1 = fmaxf(1e-6f * rr.y, 1e-12f);

  const int m  = lane & 15;               // A-frag row / B-frag n / D col
  const int qd = lane >> 4;               // quad: k-subrange qd*8..+7
  const unsigned short* arow0 = A + (size_t)(w * 32 + m) * NN + qd * 8;
  const unsigned short* arow1 = arow0 + 16 * NN;

  for (int it = 0; it < 48; ++it) {
    bool act0 = rr.x > tol0, act1 = rr.y > tol1;
    if (!act0 && !act1) break;

    // ---- build B-fragments of p (bf16, MFMA B layout) : 128 threads ----
    if (t < 128) {
      int c = t >> 3, q = (t >> 1) & 3, n = t & 1;
      const float* base = reinterpret_cast<const float*>(&p01[c * 32 + q * 8]);
      unsigned int w0 = (unsigned int)f2bf(base[0 * 2 + n]) |
                        ((unsigned int)f2bf(base[1 * 2 + n]) << 16);
      unsigned int w1 = (unsigned int)f2bf(base[2 * 2 + n]) |
                        ((unsigned int)f2bf(base[3 * 2 + n]) << 16);
      unsigned int w2 = (unsigned int)f2bf(base[4 * 2 + n]) |
                        ((unsigned int)f2bf(base[5 * 2 + n]) << 16);
      unsigned int w3 = (unsigned int)f2bf(base[6 * 2 + n]) |
                        ((unsigned int)f2bf(base[7 * 2 + n]) << 16);
      *reinterpret_cast<uint4*>(&pbf[c][q][n][0]) = make_uint4(w0, w1, w2, w3);
    }
    __syncthreads();

    // ---- matvec: 16 k-chunks of 32, two 16-row tiles per wave ----
    ffrag acc0 = {0.f, 0.f, 0.f, 0.f};
    ffrag acc1 = {0.f, 0.f, 0.f, 0.f};
    #pragma unroll 4
    for (int c = 0; c < 16; ++c) {
      bfrag bf = *reinterpret_cast<const bfrag*>(&pbf[c][qd][m][0]);
      bfrag a0 = *reinterpret_cast<const bfrag*>(arow0 + c * 32);
      bfrag a1 = *reinterpret_cast<const bfrag*>(arow1 + c * 32);
      acc0 = __builtin_amdgcn_mfma_f32_16x16x32_bf16(a0, bf, acc0, 0, 0, 0);
      acc1 = __builtin_amdgcn_mfma_f32_16x16x32_bf16(a1, bf, acc1, 0, 0, 0);
    }
    // D layout: col=lane&15, row=(lane>>4)*4+reg  -> cols 0,1 are the 2 RHS
    if (m < 2) {
      int rbase = qd * 4;
      #pragma unroll
      for (int r = 0; r < 4; ++r) {
        reinterpret_cast<float*>(&q01[w * 32 + rbase + r])[m]      = acc0[r];
        reinterpret_cast<float*>(&q01[w * 32 + 16 + rbase + r])[m] = acc1[r];
      }
    }
    __syncthreads();

    // ---- alpha = rr / p.q ----
    float2 dv = z2;
    if (t < NN) {
      float2 pv = p01[t], qv = q01[t];
      dv.x = qv.x * pv.x;
      dv.y = qv.y * pv.y;
    }
    float2 pq = blockReduce2(dv, wred, t);
    float al0 = act0 ? rr.x / pq.x : 0.f;
    float al1 = act1 ? rr.y / pq.y : 0.f;
    float2 rn = z2;
    if (t < NN) {
      float2 xv = x01[t], rv = r01[t], pv = p01[t], qv = q01[t];
      xv.x = fmaf(al0, pv.x, xv.x);  xv.y = fmaf(al1, pv.y, xv.y);
      rv.x = fmaf(-al0, qv.x, rv.x); rv.y = fmaf(-al1, qv.y, rv.y);
      x01[t] = xv; r01[t] = rv;
      rn.x = rv.x * rv.x; rn.y = rv.y * rv.y;
    }
    float2 rrn = blockReduce2(rn, wred, t);
    float be0 = act0 ? rrn.x / rr.x : 0.f;
    float be1 = act1 ? rrn.y / rr.y : 0.f;
    if (t < NN) {
      float2 rv = r01[t], pv = p01[t];
      pv.x = fmaf(be0, pv.x, rv.x);
      pv.y = fmaf(be1, pv.y, rv.y);
      p01[t] = pv;
    }
    rr = rrn;
    __syncthreads();                        // p01 ready for next B-frag build
  }

  float2 sv = z2;
  if (t < NN) sv = x01[t];
  float2 s = blockReduce2(sv, wred, t);
  float lam = (s.x - tq[b]) / s.y;
  if (t < NN) qout[b * NN + t] = x01[t].x - lam * x01[t].y;
}

// ---------------- fp32 fallback (round-3 structure, looser tol) --------------
__global__ __launch_bounds__(1024) void cg_kernel_f32(
    const float* __restrict__ Aall, const float* __restrict__ tq,
    float* __restrict__ qout)
{
  int b = blockIdx.x;
  const float* A = Aall + (size_t)b * NN * NN;
  int t = threadIdx.x;
  __shared__ float2 p01[NN], q01[NN], r01[NN], x01[NN];
  __shared__ float4 sacc0[8][128];
  __shared__ float4 sacc1[8][128];
  __shared__ float2 wred[16];

  float2 z2 = make_float2(0.f, 0.f);
  float2 rsq = z2;
  if (t < NN) {
    float b0 = -qout[b * NN + t];
    x01[t] = z2;
    r01[t] = make_float2(b0, 1.0f);
    p01[t] = make_float2(b0, 1.0f);
    rsq = make_float2(b0 * b0, 1.0f);
  }
  float2 rr = blockReduce2(rsq, wred, t);
  float tol0 = fmaxf(1e-6f * rr.x, 1e-12f);
  float tol1 = fmaxf(1e-6f * rr.y, 1e-12f);
  const int c4 = (t & 127) << 2;
  const int jr = t >> 7;
  for (int it = 0; it < 48; ++it) {
    bool act0 = rr.x > tol0, act1 = rr.y > tol1;
    if (!act0 && !act1) break;
    {
      const float* ap = A + (size_t)(jr * 64) * NN + c4;
      float4 a0 = make_float4(0.f, 0.f, 0.f, 0.f);
      float4 a1 = a0;
      #pragma unroll 8
      for (int mI = 0; mI < 64; ++mI) {
        float4 av = *reinterpret_cast<const float4*>(ap);
        ap += NN;
        float2 pj = p01[jr * 64 + mI];
        a0.x = fmaf(av.x, pj.x, a0.x); a0.y = fmaf(av.y, pj.x, a0.y);
        a0.z = fmaf(av.z, pj.x, a0.z); a0.w = fmaf(av.w, pj.x, a0.w);
        a1.x = fmaf(av.x, pj.y, a1.x); a1.y = fmaf(av.y, pj.y, a1.y);
        a1.z = fmaf(av.z, pj.y, a1.z); a1.w = fmaf(av.w, pj.y, a1.w);
      }
      sacc0[jr][t & 127] = a0;
      sacc1[jr][t & 127] = a1;
    }
    __syncthreads();
    float2 dv = z2;
    if (t < NN) {
      const float* f0 = reinterpret_cast<const float*>(sacc0);
      const float* f1 = reinterpret_cast<const float*>(sacc1);
      float s0 = 0.f, s1 = 0.f;
      #pragma unroll
      for (int g = 0; g < 8; ++g) { s0 += f0[g * 512 + t]; s1 += f1[g * 512 + t]; }
      q01[t] = make_float2(s0, s1);
      float2 pv = p01[t];
      dv.x = s0 * pv.x; dv.y = s1 * pv.y;
    }
    float2 pq = blockReduce2(dv, wred, t);
    float al0 = act0 ? rr.x / pq.x : 0.f;
    float al1 = act1 ? rr.y / pq.y : 0.f;
    float2 rn = z2;
    if (t < NN) {
      float2 xv = x01[t], rv = r01[t], pv = p01[t], qv = q01[t];
      xv.x = fmaf(al0, pv.x, xv.x);  xv.y = fmaf(al1, pv.y, xv.y);
      rv.x = fmaf(-al0, qv.x, rv.x); rv.y = fmaf(-al1, qv.y, rv.y);
      x01[t] = xv; r01[t] = rv;
      rn.x = rv.x * rv.x; rn.y = rv.y * rv.y;
    }
    float2 rrn = blockReduce2(rn, wred, t);
    float be0 = act0 ? rrn.x / rr.x : 0.f;
    float be1 = act1 ? rrn.y / rr.y : 0.f;
    if (t < NN) {
      float2 rv = r01[t], pv = p01[t];
      pv.x = fmaf(be0, pv.x, rv.x);
      pv.y = fmaf(be1, pv.y, rv.y);
      p01[t] = pv;
    }
    rr = rrn;
    __syncthreads();
  }
  float2 sv = z2;
  if (t < NN) sv = x01[t];
  float2 s = blockReduce2(sv, wred, t);
  float lam = (s.x - tq[b]) / s.y;
  if (t < NN) qout[b * NN + t] = x01[t].x - lam * x01[t].y;
}

extern "C" void kernel_launch(void* const* d_in, const int* in_sizes, int n_in,
                              void* d_out, int out_size, void* d_ws, size_t ws_size,
                              hipStream_t stream) {
  const float* pos      = (const float*)d_in[0];
  const float* feats    = (const float*)d_in[1];
  const int*   ntype    = (const int*)  d_in[2];
  const float* tq       = (const float*)d_in[3];
  const float* hardness = (const float*)d_in[4];
  const float* sigma    = (const float*)d_in[5];
  const float* W1 = (const float*)d_in[6];
  const float* b1 = (const float*)d_in[7];
  const float* W2 = (const float*)d_in[8];
  const float* b2 = (const float*)d_in[9];
  const float* W3 = (const float*)d_in[10];
  const float* b3 = (const float*)d_in[11];

  float* out  = (float*)d_out;
  float* chi  = out;             // charges region doubles as chi scratch
  float* Aout = out + BB * NN;   // output 1: A, batch-major

  const size_t bf_bytes = (size_t)BB * NN * NN * sizeof(unsigned short);
  const bool use_bf = ws_size >= bf_bytes;
  unsigned short* Abf = use_bf ? (unsigned short*)d_ws : nullptr;

  chi_kernel<<<dim3(BB * NN / 4), dim3(256), 0, stream>>>(feats, W1, b1, W2, b2, W3, b3, chi);
  build_A_kernel<<<dim3(NN / 16, BB), dim3(256), 0, stream>>>(pos, ntype, hardness, sigma, Aout, Abf);
  if (use_bf)
    cg_kernel_bf<<<dim3(BB), dim3(1024), 0, stream>>>(Abf, tq, chi);
  else
    cg_kernel_f32<<<dim3(BB), dim3(1024), 0, stream>>>(Aout, tq, chi);
}

// Round 6
// 330.866 us; speedup vs baseline: 1.9979x; 1.9979x over previous
//
#include <hip/hip_runtime.h>
#include <math.h>

constexpr int BB = 64, NN = 512, DD = 128, UU = 64;
constexpr float KCOUL = 14.399645351950548f;
constexpr float NOISEF = 1e-8f;
#define M_PIF 3.14159265358979323846f

typedef __attribute__((ext_vector_type(8))) short bfrag;   // 8 bf16 (4 VGPRs)
typedef __attribute__((ext_vector_type(4))) float ffrag;   // 4 fp32 acc

__device__ __forceinline__ unsigned short f2bf(float f) {   // RNE float->bf16
  unsigned int u = __float_as_uint(f);
  u += 0x7fffu + ((u >> 16) & 1u);
  return (unsigned short)(u >> 16);
}
__device__ __forceinline__ float bf2f(unsigned short h) {
  return __uint_as_float((unsigned int)h << 16);
}

// ---------------- chi MLP: one wave (64 lanes) per row, 4 rows/block ----------
__global__ __launch_bounds__(256) void chi_kernel(
    const float* __restrict__ feats, const float* __restrict__ W1,
    const float* __restrict__ b1, const float* __restrict__ W2,
    const float* __restrict__ b2, const float* __restrict__ W3,
    const float* __restrict__ b3, float* __restrict__ chi)
{
  int wave = threadIdx.x >> 6, lane = threadIdx.x & 63;
  int row = (blockIdx.x << 2) + wave;
  __shared__ float sf[4][DD];
  __shared__ float sh[4][UU];
  const float* f = feats + (size_t)row * DD;
  sf[wave][lane] = f[lane];
  sf[wave][lane + 64] = f[lane + 64];
  __syncthreads();
  float a = b1[lane];
  #pragma unroll 8
  for (int d = 0; d < DD; ++d) a = fmaf(sf[wave][d], W1[d * UU + lane], a);
  float h1 = a - tanhf(a);            // tanhshrink
  sh[wave][lane] = h1;
  __syncthreads();
  float a2 = b2[lane];
  #pragma unroll 8
  for (int i = 0; i < UU; ++i) a2 = fmaf(sh[wave][i], W2[i * UU + lane], a2);
  float h2 = a2 - tanhf(a2);
  float prod = h2 * W3[lane];
  #pragma unroll
  for (int off = 32; off; off >>= 1) prod += __shfl_down(prod, off, 64);
  if (lane == 0) {
    float z = prod + b3[0];
    chi[row] = z - tanhf(z);
  }
}

// ------ build A (fp32 to d_out) + bf16 copy in MFMA fragment-major layout ----
// swizzle: (i,j) -> (i>>4)*8192 + (j>>5)*512 + ((j>>3)&3)*128 + (i&15)*8 + (j&7)
// so wave-tile t0, chunk c: lane(m,qd) reads 8 shorts at lane*8 -> 1KB/wave.
__global__ __launch_bounds__(256) void build_A_kernel(
    const float* __restrict__ pos, const int* __restrict__ ntype,
    const float* __restrict__ hardness, const float* __restrict__ sigma,
    float* __restrict__ Aout, unsigned short* __restrict__ Abf)
{
  int b = blockIdx.y;
  int r0 = blockIdx.x * 16;
  __shared__ float px[NN], py[NN], pz[NN], s2[NN], hd[NN];
  for (int n = threadIdx.x; n < NN; n += 256) {
    const float* p = pos + ((size_t)b * NN + n) * 3;
    px[n] = p[0]; py[n] = p[1]; pz[n] = p[2];
    int ty = ntype[b * NN + n];
    float s = sigma[ty];
    s2[n] = s * s;
    hd[n] = hardness[ty];
  }
  __syncthreads();
  int c0 = (threadIdx.x & 127) << 2;
  int rsub = threadIdx.x >> 7;
  float* outB = Aout + (size_t)b * NN * NN;
  unsigned short* bfB = Abf ? Abf + (size_t)b * NN * NN : nullptr;
  for (int k = 0; k < 8; ++k) {
    int i = r0 + (k << 1) + rsub;
    float pxi = px[i], pyi = py[i], pzi = pz[i], s2i = s2[i];
    float4 v;
    float* vp = &v.x;
    #pragma unroll
    for (int c = 0; c < 4; ++c) {
      int j = c0 + c;
      float dx = pxi - px[j], dy = pyi - py[j], dz = pzi - pz[j];
      float d = sqrtf(fmaf(dx, dx, fmaf(dy, dy, dz * dz))) + NOISEF;
      float arg = d * rsqrtf(2.0f * (s2i + s2[j]));
      float val = KCOUL * erff(arg) / d;
      if (j == i) val += hd[i] + KCOUL * rsqrtf(2.0f * M_PIF * s2i);
      vp[c] = val;
    }
    *reinterpret_cast<float4*>(outB + (size_t)i * NN + c0) = v;
    if (bfB) {
      ushort4 wv;
      wv.x = f2bf(v.x); wv.y = f2bf(v.y); wv.z = f2bf(v.z); wv.w = f2bf(v.w);
      size_t off = ((size_t)(i >> 4) << 13) + ((size_t)(c0 >> 5) << 9)
                 + (((c0 >> 3) & 3) << 7) + ((i & 15) << 3) + (c0 & 7);
      *reinterpret_cast<ushort4*>(bfB + off) = wv;   // 8B aligned (c0&7 in {0,4})
    }
  }
}

// ---------------- shared reduction helper ------------------------------------
__device__ __forceinline__ float2 blockReduce2(float2 v, float2* wred, int t) {
  #pragma unroll
  for (int off = 32; off; off >>= 1) {
    v.x += __shfl_down(v.x, off, 64);
    v.y += __shfl_down(v.y, off, 64);
  }
  __syncthreads();
  if ((t & 63) == 0) wred[t >> 6] = v;
  __syncthreads();
  float2 r = wred[0];
  #pragma unroll
  for (int k = 1; k < 16; ++k) { r.x += wred[k].x; r.y += wred[k].y; }
  return r;
}

// ------- MFMA hi/lo matvec 2-RHS CG, one 1024-thread block per batch ---------
// q = A(bf16)·p_hi + A(bf16)·p_lo  with p_hi=bf16(p), p_lo=bf16(p-p_hi):
// p enters at ~15-bit precision -> same numerics as the fp32-p round-4 kernel.
__global__ __launch_bounds__(1024) void cg_kernel_bf(
    const unsigned short* __restrict__ Abf, const float* __restrict__ tq,
    float* __restrict__ qout /* in: chi, out: charges */)
{
  int b = blockIdx.x;
  const unsigned short* A = Abf + (size_t)b * NN * NN;
  int t = threadIdx.x;
  int lane = t & 63, w = t >> 6;          // 16 waves
  __shared__ float2 p01[NN], q01[NN], r01[NN], x01[NN];
  __shared__ __align__(16) unsigned short phi0[NN], phi1[NN];
  __shared__ __align__(16) unsigned short plo0[NN], plo1[NN];
  __shared__ float2 wred[16];

  float2 z2 = make_float2(0.f, 0.f);
  float2 rsq = z2;
  if (t < NN) {
    float b0 = -qout[b * NN + t];          // rhs0 = -chi ; rhs1 = ones
    x01[t] = z2;
    r01[t] = make_float2(b0, 1.0f);
    p01[t] = make_float2(b0, 1.0f);
    rsq = make_float2(b0 * b0, 1.0f);
  }
  float2 rr = blockReduce2(rsq, wred, t);  // also publishes p01
  float tol0 = fmaxf(1e-6f * rr.x, 1e-12f);   // rel residual 1e-3
  float tol1 = fmaxf(1e-6f * rr.y, 1e-12f);

  const int m  = lane & 15;               // A row within tile / D col (=rhs)
  const int qd = lane >> 4;               // quad: k-subrange qd*8..+7
  // fragment-major A: wave w owns tiles 2w, 2w+1 (rows w*32 .. w*32+31)
  const unsigned short* aw0 = A + ((size_t)(2 * w) << 13) + lane * 8;
  const unsigned short* aw1 = aw0 + 8192;
  const unsigned short* bhi = (m & 1) ? phi1 : phi0;  // n>=2 lanes: don't-care
  const unsigned short* blo = (m & 1) ? plo1 : plo0;

  for (int it = 0; it < 48; ++it) {
    bool act0 = rr.x > tol0, act1 = rr.y > tol1;
    if (!act0 && !act1) break;

    // ---- split p into bf16 hi/lo (both RHS), flat coalesced ----
    if (t < NN) {
      float2 pv = p01[t];
      unsigned short h0 = f2bf(pv.x), h1 = f2bf(pv.y);
      phi0[t] = h0; phi1[t] = h1;
      plo0[t] = f2bf(pv.x - bf2f(h0));
      plo1[t] = f2bf(pv.y - bf2f(h1));
    }
    __syncthreads();

    // ---- matvec: 16 k-chunks of 32, two 16-row tiles per wave ----
    ffrag acc0 = {0.f, 0.f, 0.f, 0.f};
    ffrag acc1 = {0.f, 0.f, 0.f, 0.f};
    #pragma unroll 4
    for (int c = 0; c < 16; ++c) {
      int bo = c * 32 + qd * 8;
      bfrag bh = *reinterpret_cast<const bfrag*>(bhi + bo);  // LDS broadcast
      bfrag bl = *reinterpret_cast<const bfrag*>(blo + bo);
      bfrag a0 = *reinterpret_cast<const bfrag*>(aw0 + c * 512);  // 1KB/wave
      bfrag a1 = *reinterpret_cast<const bfrag*>(aw1 + c * 512);
      acc0 = __builtin_amdgcn_mfma_f32_16x16x32_bf16(a0, bh, acc0, 0, 0, 0);
      acc0 = __builtin_amdgcn_mfma_f32_16x16x32_bf16(a0, bl, acc0, 0, 0, 0);
      acc1 = __builtin_amdgcn_mfma_f32_16x16x32_bf16(a1, bh, acc1, 0, 0, 0);
      acc1 = __builtin_amdgcn_mfma_f32_16x16x32_bf16(a1, bl, acc1, 0, 0, 0);
    }
    // D layout: col=lane&15 (rhs), row=qd*4+reg ; only cols 0,1 are read
    if (m < 2) {
      int rbase = qd * 4;
      #pragma unroll
      for (int r = 0; r < 4; ++r) {
        reinterpret_cast<float*>(&q01[w * 32 + rbase + r])[m]      = acc0[r];
        reinterpret_cast<float*>(&q01[w * 32 + 16 + rbase + r])[m] = acc1[r];
      }
    }
    __syncthreads();

    // ---- alpha = rr / p.q ----
    float2 dv = z2;
    if (t < NN) {
      float2 pv = p01[t], qv = q01[t];
      dv.x = qv.x * pv.x;
      dv.y = qv.y * pv.y;
    }
    float2 pq = blockReduce2(dv, wred, t);
    float al0 = act0 ? rr.x / pq.x : 0.f;
    float al1 = act1 ? rr.y / pq.y : 0.f;
    float2 rn = z2;
    if (t < NN) {
      float2 xv = x01[t], rv = r01[t], pv = p01[t], qv = q01[t];
      xv.x = fmaf(al0, pv.x, xv.x);  xv.y = fmaf(al1, pv.y, xv.y);
      rv.x = fmaf(-al0, qv.x, rv.x); rv.y = fmaf(-al1, qv.y, rv.y);
      x01[t] = xv; r01[t] = rv;
      rn.x = rv.x * rv.x; rn.y = rv.y * rv.y;
    }
    float2 rrn = blockReduce2(rn, wred, t);
    float be0 = act0 ? rrn.x / rr.x : 0.f;
    float be1 = act1 ? rrn.y / rr.y : 0.f;
    if (t < NN) {
      float2 rv = r01[t], pv = p01[t];
      pv.x = fmaf(be0, pv.x, rv.x);
      pv.y = fmaf(be1, pv.y, rv.y);
      p01[t] = pv;
    }
    rr = rrn;
    __syncthreads();                        // p01 ready for next hi/lo split
  }

  float2 sv = z2;
  if (t < NN) sv = x01[t];
  float2 s = blockReduce2(sv, wred, t);
  float lam = (s.x - tq[b]) / s.y;
  if (t < NN) qout[b * NN + t] = x01[t].x - lam * x01[t].y;
}

// ---------------- fp32 fallback (round-3 structure, looser tol) --------------
__global__ __launch_bounds__(1024) void cg_kernel_f32(
    const float* __restrict__ Aall, const float* __restrict__ tq,
    float* __restrict__ qout)
{
  int b = blockIdx.x;
  const float* A = Aall + (size_t)b * NN * NN;
  int t = threadIdx.x;
  __shared__ float2 p01[NN], q01[NN], r01[NN], x01[NN];
  __shared__ float4 sacc0[8][128];
  __shared__ float4 sacc1[8][128];
  __shared__ float2 wred[16];

  float2 z2 = make_float2(0.f, 0.f);
  float2 rsq = z2;
  if (t < NN) {
    float b0 = -qout[b * NN + t];
    x01[t] = z2;
    r01[t] = make_float2(b0, 1.0f);
    p01[t] = make_float2(b0, 1.0f);
    rsq = make_float2(b0 * b0, 1.0f);
  }
  float2 rr = blockReduce2(rsq, wred, t);
  float tol0 = fmaxf(1e-6f * rr.x, 1e-12f);
  float tol1 = fmaxf(1e-6f * rr.y, 1e-12f);
  const int c4 = (t & 127) << 2;
  const int jr = t >> 7;
  for (int it = 0; it < 48; ++it) {
    bool act0 = rr.x > tol0, act1 = rr.y > tol1;
    if (!act0 && !act1) break;
    {
      const float* ap = A + (size_t)(jr * 64) * NN + c4;
      float4 a0 = make_float4(0.f, 0.f, 0.f, 0.f);
      float4 a1 = a0;
      #pragma unroll 8
      for (int mI = 0; mI < 64; ++mI) {
        float4 av = *reinterpret_cast<const float4*>(ap);
        ap += NN;
        float2 pj = p01[jr * 64 + mI];
        a0.x = fmaf(av.x, pj.x, a0.x); a0.y = fmaf(av.y, pj.x, a0.y);
        a0.z = fmaf(av.z, pj.x, a0.z); a0.w = fmaf(av.w, pj.x, a0.w);
        a1.x = fmaf(av.x, pj.y, a1.x); a1.y = fmaf(av.y, pj.y, a1.y);
        a1.z = fmaf(av.z, pj.y, a1.z); a1.w = fmaf(av.w, pj.y, a1.w);
      }
      sacc0[jr][t & 127] = a0;
      sacc1[jr][t & 127] = a1;
    }
    __syncthreads();
    float2 dv = z2;
    if (t < NN) {
      const float* f0 = reinterpret_cast<const float*>(sacc0);
      const float* f1 = reinterpret_cast<const float*>(sacc1);
      float s0 = 0.f, s1 = 0.f;
      #pragma unroll
      for (int g = 0; g < 8; ++g) { s0 += f0[g * 512 + t]; s1 += f1[g * 512 + t]; }
      q01[t] = make_float2(s0, s1);
      float2 pv = p01[t];
      dv.x = s0 * pv.x; dv.y = s1 * pv.y;
    }
    float2 pq = blockReduce2(dv, wred, t);
    float al0 = act0 ? rr.x / pq.x : 0.f;
    float al1 = act1 ? rr.y / pq.y : 0.f;
    float2 rn = z2;
    if (t < NN) {
      float2 xv = x01[t], rv = r01[t], pv = p01[t], qv = q01[t];
      xv.x = fmaf(al0, pv.x, xv.x);  xv.y = fmaf(al1, pv.y, xv.y);
      rv.x = fmaf(-al0, qv.x, rv.x); rv.y = fmaf(-al1, qv.y, rv.y);
      x01[t] = xv; r01[t] = rv;
      rn.x = rv.x * rv.x; rn.y = rv.y * rv.y;
    }
    float2 rrn = blockReduce2(rn, wred, t);
    float be0 = act0 ? rrn.x / rr.x : 0.f;
    float be1 = act1 ? rrn.y / rr.y : 0.f;
    if (t < NN) {
      float2 rv = r01[t], pv = p01[t];
      pv.x = fmaf(be0, pv.x, rv.x);
      pv.y = fmaf(be1, pv.y, rv.y);
      p01[t] = pv;
    }
    rr = rrn;
    __syncthreads();
  }
  float2 sv = z2;
  if (t < NN) sv = x01[t];
  float2 s = blockReduce2(sv, wred, t);
  float lam = (s.x - tq[b]) / s.y;
  if (t < NN) qout[b * NN + t] = x01[t].x - lam * x01[t].y;
}

extern "C" void kernel_launch(void* const* d_in, const int* in_sizes, int n_in,
                              void* d_out, int out_size, void* d_ws, size_t ws_size,
                              hipStream_t stream) {
  const float* pos      = (const float*)d_in[0];
  const float* feats    = (const float*)d_in[1];
  const int*   ntype    = (const int*)  d_in[2];
  const float* tq       = (const float*)d_in[3];
  const float* hardness = (const float*)d_in[4];
  const float* sigma    = (const float*)d_in[5];
  const float* W1 = (const float*)d_in[6];
  const float* b1 = (const float*)d_in[7];
  const float* W2 = (const float*)d_in[8];
  const float* b2 = (const float*)d_in[9];
  const float* W3 = (const float*)d_in[10];
  const float* b3 = (const float*)d_in[11];

  float* out  = (float*)d_out;
  float* chi  = out;             // charges region doubles as chi scratch
  float* Aout = out + BB * NN;   // output 1: A, batch-major

  const size_t bf_bytes = (size_t)BB * NN * NN * sizeof(unsigned short);
  const bool use_bf = ws_size >= bf_bytes;
  unsigned short* Abf = use_bf ? (unsigned short*)d_ws : nullptr;

  chi_kernel<<<dim3(BB * NN / 4), dim3(256), 0, stream>>>(feats, W1, b1, W2, b2, W3, b3, chi);
  build_A_kernel<<<dim3(NN / 16, BB), dim3(256), 0, stream>>>(pos, ntype, hardness, sigma, Aout, Abf);
  if (use_bf)
    cg_kernel_bf<<<dim3(BB), dim3(1024), 0, stream>>>(Abf, tq, chi);
  else
    cg_kernel_f32<<<dim3(BB), dim3(1024), 0, stream>>>(Aout, tq, chi);
}